// Round 1
// baseline (355.953 us; speedup 1.0000x reference)
//
#include <hip/hip_runtime.h>
#include <math.h>

// Problem constants
#define Bz 4
#define Tz 2048
#define Cz 1024
#define Hz 16
#define DHz 64
#define Mz (Bz*Tz)          // 8192

typedef __attribute__((ext_vector_type(8))) short short8;
typedef __attribute__((ext_vector_type(4))) float f32x4;
typedef __attribute__((ext_vector_type(4))) float flt4;

__device__ inline unsigned short f2bf(float f){
  union { float f; unsigned int u; } x; x.f = f;
  unsigned int r = x.u + 0x7fffu + ((x.u >> 16) & 1u);
  return (unsigned short)(r >> 16);
}
__device__ inline float bf2f(unsigned short b){
  union { unsigned int u; float f; } x; x.u = ((unsigned int)b) << 16; return x.f;
}

__device__ inline void gload_lds16(const unsigned short* g, char* l){
  __builtin_amdgcn_global_load_lds((const __attribute__((address_space(1))) unsigned int*)g,
                                   (__attribute__((address_space(3))) unsigned int*)l,
                                   16, 0, 0);
}

// ---------------- fp32 -> bf16 convert ----------------
__global__ __launch_bounds__(256) void cvt_bf16(const float* __restrict__ src,
                                                unsigned short* __restrict__ dst, int n){
  int i = (blockIdx.x * 256 + threadIdx.x) * 4;
  if (i + 3 < n){
    flt4 v = *(const flt4*)(src + i);
    unsigned short o0 = f2bf(v.x), o1 = f2bf(v.y), o2 = f2bf(v.z), o3 = f2bf(v.w);
    unsigned long long pack = (unsigned long long)o0 | ((unsigned long long)o1 << 16)
                            | ((unsigned long long)o2 << 32) | ((unsigned long long)o3 << 48);
    *(unsigned long long*)(dst + i) = pack;
  }
}

// ---------------- GEMM: C = A * B^T (A: MxK, Bw: NxK, both bf16 row-major) ----
// 128x128 tile, BK=64, 4 waves (2x2), 16x16x32 bf16 MFMA.
// LDS tiles stored with T2 st-style XOR swizzle applied via pre-swizzled
// global source (global_load_lds writes linearly; read applies same XOR).
// EPI==0: scatter to q/k/v [B,H,T,DH] bf16.  EPI==1: plain fp32 store.
template<int EPI>
__global__ __launch_bounds__(256)
void gemm_bt(const unsigned short* __restrict__ A, const unsigned short* __restrict__ Bw,
             const int K,
             unsigned short* __restrict__ qd, unsigned short* __restrict__ kd,
             unsigned short* __restrict__ vd, float* __restrict__ outf)
{
  __shared__ __align__(16) char lds[32768];
  char* At = lds;           // [128 rows][64 bf16 = 128B], swizzled content
  char* Bt = lds + 16384;

  const int tid  = threadIdx.x;
  const int lane = tid & 63, wid = tid >> 6;
  const int l16  = lane & 15, lg = lane >> 4;
  const int wr   = wid >> 1, wc = wid & 1;
  const int m0   = blockIdx.y * 128, n0 = blockIdx.x * 128;

  f32x4 acc[4][4] = {};
  const int nk = K >> 6;

  for (int kt = 0; kt < nk; ++kt){
    const unsigned short* As = A  + (size_t)m0 * K + kt * 64;
    const unsigned short* Bs = Bw + (size_t)n0 * K + kt * 64;
    #pragma unroll
    for (int it = 0; it < 4; ++it){
      int id  = it * 256 + tid;
      int row = id >> 3, c = id & 7;
      int sc  = c ^ (row & 7);                 // pre-swizzle global source (m201 pattern)
      char* dA = At + (it * 256 + wid * 64) * 16;
      char* dB = Bt + (it * 256 + wid * 64) * 16;
      gload_lds16(As + (size_t)row * K + sc * 8, dA);
      gload_lds16(Bs + (size_t)row * K + sc * 8, dB);
    }
    __syncthreads();

    #pragma unroll
    for (int ks = 0; ks < 2; ++ks){
      short8 af[4], bf[4];
      #pragma unroll
      for (int mt = 0; mt < 4; ++mt){
        int row = wr * 64 + mt * 16 + l16;
        af[mt] = *(const short8*)(At + row * 128 + (((ks * 4 + lg) ^ (row & 7)) << 4));
      }
      #pragma unroll
      for (int nt = 0; nt < 4; ++nt){
        int row = wc * 64 + nt * 16 + l16;
        bf[nt] = *(const short8*)(Bt + row * 128 + (((ks * 4 + lg) ^ (row & 7)) << 4));
      }
      #pragma unroll
      for (int mt = 0; mt < 4; ++mt)
        #pragma unroll
        for (int nt = 0; nt < 4; ++nt)
          acc[mt][nt] = __builtin_amdgcn_mfma_f32_16x16x32_bf16(af[mt], bf[nt], acc[mt][nt], 0, 0, 0);
    }
    __syncthreads();
  }

  // Epilogue: C/D layout col = lane&15, row = (lane>>4)*4 + i   (m89-verified)
  #pragma unroll
  for (int mt = 0; mt < 4; ++mt){
    #pragma unroll
    for (int nt = 0; nt < 4; ++nt){
      #pragma unroll
      for (int i = 0; i < 4; ++i){
        int m = m0 + wr * 64 + mt * 16 + lg * 4 + i;
        int n = n0 + wc * 64 + nt * 16 + l16;
        float val = acc[mt][nt][i];
        if (EPI == 0){
          int part = n >> 10, c = n & 1023;
          int h = c >> 6,  d = c & 63;
          int b = m >> 11, t = m & 2047;
          unsigned short* dst = (part == 0) ? qd : ((part == 1) ? kd : vd);
          dst[(((size_t)(b * Hz + h)) * Tz + t) * DHz + d] = f2bf(val);
        } else {
          outf[(size_t)m * 1024 + n] = val;
        }
      }
    }
  }
}

// ---------------- RoPE in-place on q,k ([B*H][T][DH] bf16); q also * 1/8 ----
__global__ __launch_bounds__(256) void rope_kernel(unsigned short* __restrict__ qh,
                                                   unsigned short* __restrict__ kh,
                                                   const float* __restrict__ cosb,
                                                   const float* __restrict__ sinb){
  unsigned int idx = blockIdx.x * 256 + threadIdx.x;   // 2^23 total
  int i   = idx & 31;
  int row = (idx >> 5) & 131071;                        // B*H*T = 2^17 rows
  int buf = idx >> 22;
  unsigned short* p = (buf ? kh : qh) + (size_t)row * DHz + 2 * i;
  int t = row & (Tz - 1);
  float c = cosb[t * 32 + i], s = sinb[t * 32 + i];
  unsigned int pr = *(const unsigned int*)p;
  float x1 = bf2f((unsigned short)(pr & 0xffff));
  float x2 = bf2f((unsigned short)(pr >> 16));
  float r1 = x1 * c - x2 * s;
  float r2 = x1 * s + x2 * c;
  if (!buf){ r1 *= 0.125f; r2 *= 0.125f; }             // fold 1/sqrt(DH) into q
  *(unsigned int*)p = (unsigned int)f2bf(r1) | ((unsigned int)f2bf(r2) << 16);
}

// ---------------- Flash attention (causal), bf16 in, bf16 out -----------------
// Block = 4 waves; block handles 64 q-rows of one (b,h); wave owns 16 rows.
__global__ __launch_bounds__(256)
void attn_fwd(const unsigned short* __restrict__ qh, const unsigned short* __restrict__ kh,
              const unsigned short* __restrict__ vh, unsigned short* __restrict__ y)
{
  __shared__ __align__(16) char lds[8192 + 9216 + 9216];
  char* KL = lds;                 // [64][64] bf16, swizzled content (gload_lds)
  char* VL = lds + 8192;          // Vt: [64 d][72 kv] bf16 (padded, manual stage)
  char* PL = lds + 8192 + 9216;   // per wave: [16][72] bf16

  const int tid  = threadIdx.x;
  const int lane = tid & 63, wid = tid >> 6;
  const int l16  = lane & 15, lg = lane >> 4;
  const int bh   = blockIdx.x;    // 0..63
  const int qt   = blockIdx.y;    // 0..31

  const size_t base = (size_t)bh * Tz * DHz;
  const unsigned short* qb = qh + base;
  const unsigned short* kb = kh + base;
  const unsigned short* vb = vh + base;

  // Q fragments stay in registers (rows = wave's 16 q rows)
  short8 qf[2];
  {
    int qrow = qt * 64 + wid * 16 + l16;
    qf[0] = *(const short8*)(qb + (size_t)qrow * DHz + 0  + lg * 8);
    qf[1] = *(const short8*)(qb + (size_t)qrow * DHz + 32 + lg * 8);
  }

  f32x4 o[4] = {};
  float m_r[4] = {-INFINITY, -INFINITY, -INFINITY, -INFINITY};
  float l_r[4] = {};
  unsigned short* Pw = (unsigned short*)(PL + wid * 2304);

  for (int kt = 0; kt <= qt; ++kt){
    // stage K tile (swizzled via pre-swizzled global src + global_load_lds)
    const unsigned short* Ks = kb + (size_t)kt * 64 * DHz;
    #pragma unroll
    for (int it = 0; it < 2; ++it){
      int id  = it * 256 + tid;
      int row = id >> 3, c = id & 7;
      int sc  = c ^ (row & 7);
      gload_lds16(Ks + row * DHz + sc * 8, KL + (it * 256 + wid * 64) * 16);
    }
    // stage V transposed into padded LDS
    const unsigned short* Vs = vb + (size_t)kt * 64 * DHz;
    unsigned short* vt = (unsigned short*)VL;
    #pragma unroll
    for (int it = 0; it < 2; ++it){
      int id = it * 256 + tid;
      int r = id & 63, c0 = (id >> 6) * 8;
      short8 v8 = *(const short8*)(Vs + r * DHz + c0);
      #pragma unroll
      for (int j = 0; j < 8; ++j)
        vt[(c0 + j) * 72 + r] = (unsigned short)v8[j];
    }
    __syncthreads();

    // S = Q K^T  (A = Q regs, B = K tile)
    f32x4 s[4] = {};
    #pragma unroll
    for (int ks = 0; ks < 2; ++ks){
      short8 kf[4];
      #pragma unroll
      for (int nt = 0; nt < 4; ++nt){
        int row = nt * 16 + l16;
        kf[nt] = *(const short8*)(KL + row * 128 + (((ks * 4 + lg) ^ (row & 7)) << 4));
      }
      #pragma unroll
      for (int nt = 0; nt < 4; ++nt)
        s[nt] = __builtin_amdgcn_mfma_f32_16x16x32_bf16(qf[ks], kf[nt], s[nt], 0, 0, 0);
    }

    if (kt == qt){
      #pragma unroll
      for (int nt = 0; nt < 4; ++nt)
        #pragma unroll
        for (int i = 0; i < 4; ++i){
          int kv = nt * 16 + l16;
          int qr = wid * 16 + lg * 4 + i;
          if (kv > qr) s[nt][i] = -INFINITY;
        }
    }

    // online softmax (rows live across 16-lane groups; reduce via shfl_xor)
    float p[4][4];
    #pragma unroll
    for (int i = 0; i < 4; ++i){
      float mx = fmaxf(fmaxf(s[0][i], s[1][i]), fmaxf(s[2][i], s[3][i]));
      mx = fmaxf(mx, __shfl_xor(mx, 1));
      mx = fmaxf(mx, __shfl_xor(mx, 2));
      mx = fmaxf(mx, __shfl_xor(mx, 4));
      mx = fmaxf(mx, __shfl_xor(mx, 8));
      float mn = fmaxf(m_r[i], mx);
      float al = __expf(m_r[i] - mn);
      float rs = 0.f;
      #pragma unroll
      for (int nt = 0; nt < 4; ++nt){ float pv = __expf(s[nt][i] - mn); p[nt][i] = pv; rs += pv; }
      rs += __shfl_xor(rs, 1); rs += __shfl_xor(rs, 2);
      rs += __shfl_xor(rs, 4); rs += __shfl_xor(rs, 8);
      l_r[i] = l_r[i] * al + rs;
      m_r[i] = mn;
      o[0][i] *= al; o[1][i] *= al; o[2][i] *= al; o[3][i] *= al;
    }

    // P -> per-wave LDS (bf16), then PV MFMAs (wave-local, no barrier needed)
    #pragma unroll
    for (int nt = 0; nt < 4; ++nt)
      #pragma unroll
      for (int i = 0; i < 4; ++i)
        Pw[(lg * 4 + i) * 72 + nt * 16 + l16] = f2bf(p[nt][i]);

    #pragma unroll
    for (int ks = 0; ks < 2; ++ks){
      short8 pa = *(const short8*)((const char*)Pw + (l16 * 72 + ks * 32 + lg * 8) * 2);
      #pragma unroll
      for (int nt = 0; nt < 4; ++nt){
        short8 vf = *(const short8*)(VL + ((nt * 16 + l16) * 72 + ks * 32 + lg * 8) * 2);
        o[nt] = __builtin_amdgcn_mfma_f32_16x16x32_bf16(pa, vf, o[nt], 0, 0, 0);
      }
    }
    __syncthreads();   // protect K/V tiles before next stage
  }

  // epilogue: normalize, write y [B,T,C] bf16
  const int b = bh >> 4, h = bh & 15;
  unsigned short* yb = y + ((size_t)b * Tz + qt * 64 + wid * 16) * Cz + h * 64;
  #pragma unroll
  for (int i = 0; i < 4; ++i){
    float inv = 1.f / l_r[i];
    int qr = lg * 4 + i;
    #pragma unroll
    for (int nt = 0; nt < 4; ++nt)
      yb[(size_t)qr * Cz + nt * 16 + l16] = f2bf(o[nt][i] * inv);
  }
}

// ---------------- launcher ----------------
extern "C" void kernel_launch(void* const* d_in, const int* in_sizes, int n_in,
                              void* d_out, int out_size, void* d_ws, size_t ws_size,
                              hipStream_t stream)
{
  const float* x    = (const float*)d_in[0];
  const float* cosb = (const float*)d_in[1];
  const float* sinb = (const float*)d_in[2];
  const float* Wqkv = (const float*)d_in[3];
  const float* Wo   = (const float*)d_in[4];
  float* out = (float*)d_out;

  char* ws = (char*)d_ws;
  // layout (bytes): xb/y share region 0 (xb dead after QKV GEMM)
  unsigned short* xb    = (unsigned short*)(ws);                 // 16 MB
  unsigned short* yb    = xb;                                    // reuse
  unsigned short* wqkvb = (unsigned short*)(ws + 16777216);      // 6 MB
  unsigned short* wob   = (unsigned short*)(ws + 23068672);      // 2 MB
  unsigned short* qhb   = (unsigned short*)(ws + 25165824);      // 16 MB
  unsigned short* khb   = (unsigned short*)(ws + 41943040);      // 16 MB
  unsigned short* vhb   = (unsigned short*)(ws + 58720256);      // 16 MB
  // total 72 MB

  cvt_bf16<<<8192, 256, 0, stream>>>(x,    xb,    Mz * Cz);
  cvt_bf16<<<3072, 256, 0, stream>>>(Wqkv, wqkvb, 3 * Cz * Cz);
  cvt_bf16<<<1024, 256, 0, stream>>>(Wo,   wob,   Cz * Cz);

  dim3 g1(24, 64);   // N/128 = 24, M/128 = 64
  gemm_bt<0><<<g1, 256, 0, stream>>>(xb, wqkvb, Cz, qhb, khb, vhb, nullptr);

  rope_kernel<<<32768, 256, 0, stream>>>(qhb, khb, cosb, sinb);

  dim3 g2(64, 32);   // (b*h), q-tile
  attn_fwd<<<g2, 256, 0, stream>>>(qhb, khb, vhb, yb);

  dim3 g3(8, 64);    // N/128 = 8, M/128 = 64
  gemm_bt<1><<<g3, 256, 0, stream>>>(yb, wob, Cz, nullptr, nullptr, nullptr, out);
}

// Round 2
// 286.754 us; speedup vs baseline: 1.2413x; 1.2413x over previous
//
#include <hip/hip_runtime.h>
#include <math.h>

// Problem constants
#define Bz 4
#define Tz 2048
#define Cz 1024
#define Hz 16
#define DHz 64
#define Mz (Bz*Tz)          // 8192

typedef __attribute__((ext_vector_type(8))) short short8;
typedef __attribute__((ext_vector_type(4))) float f32x4;
typedef __attribute__((ext_vector_type(4))) float flt4;

__device__ inline unsigned short f2bf(float f){
  union { float f; unsigned int u; } x; x.f = f;
  unsigned int r = x.u + 0x7fffu + ((x.u >> 16) & 1u);
  return (unsigned short)(r >> 16);
}
__device__ inline float bf2f(unsigned short b){
  union { unsigned int u; float f; } x; x.u = ((unsigned int)b) << 16; return x.f;
}
// truncating 2x f32 -> packed bf16x2 (P values only; cheap, bias ~2^-9 rel)
__device__ inline unsigned int packbf2(float a, float b){
  union { float f; unsigned int u; } x, y; x.f = a; y.f = b;
  return (x.u >> 16) | (y.u & 0xffff0000u);
}

__device__ inline void gload_lds16(const unsigned short* g, char* l){
  __builtin_amdgcn_global_load_lds((const __attribute__((address_space(1))) unsigned int*)g,
                                   (__attribute__((address_space(3))) unsigned int*)l,
                                   16, 0, 0);
}

// ---------------- fp32 -> bf16 convert ----------------
__global__ __launch_bounds__(256) void cvt_bf16(const float* __restrict__ src,
                                                unsigned short* __restrict__ dst, int n){
  int i = (blockIdx.x * 256 + threadIdx.x) * 4;
  if (i + 3 < n){
    flt4 v = *(const flt4*)(src + i);
    unsigned short o0 = f2bf(v.x), o1 = f2bf(v.y), o2 = f2bf(v.z), o3 = f2bf(v.w);
    unsigned long long pack = (unsigned long long)o0 | ((unsigned long long)o1 << 16)
                            | ((unsigned long long)o2 << 32) | ((unsigned long long)o3 << 48);
    *(unsigned long long*)(dst + i) = pack;
  }
}

// ---------------- GEMM: C = A * B^T (A: MxK, Bw: NxK, both bf16 row-major) ----
template<int EPI>
__global__ __launch_bounds__(256)
void gemm_bt(const unsigned short* __restrict__ A, const unsigned short* __restrict__ Bw,
             const int K,
             unsigned short* __restrict__ qd, unsigned short* __restrict__ kd,
             unsigned short* __restrict__ vd, float* __restrict__ outf)
{
  __shared__ __align__(16) char lds[32768];
  char* At = lds;           // [128 rows][64 bf16 = 128B], swizzled content
  char* Bt = lds + 16384;

  const int tid  = threadIdx.x;
  const int lane = tid & 63, wid = tid >> 6;
  const int l16  = lane & 15, lg = lane >> 4;
  const int wr   = wid >> 1, wc = wid & 1;
  const int m0   = blockIdx.y * 128, n0 = blockIdx.x * 128;

  f32x4 acc[4][4] = {};
  const int nk = K >> 6;

  for (int kt = 0; kt < nk; ++kt){
    const unsigned short* As = A  + (size_t)m0 * K + kt * 64;
    const unsigned short* Bs = Bw + (size_t)n0 * K + kt * 64;
    #pragma unroll
    for (int it = 0; it < 4; ++it){
      int id  = it * 256 + tid;
      int row = id >> 3, c = id & 7;
      int sc  = c ^ (row & 7);                 // pre-swizzle global source
      char* dA = At + (it * 256 + wid * 64) * 16;
      char* dB = Bt + (it * 256 + wid * 64) * 16;
      gload_lds16(As + (size_t)row * K + sc * 8, dA);
      gload_lds16(Bs + (size_t)row * K + sc * 8, dB);
    }
    __syncthreads();

    #pragma unroll
    for (int ks = 0; ks < 2; ++ks){
      short8 af[4], bf[4];
      #pragma unroll
      for (int mt = 0; mt < 4; ++mt){
        int row = wr * 64 + mt * 16 + l16;
        af[mt] = *(const short8*)(At + row * 128 + (((ks * 4 + lg) ^ (row & 7)) << 4));
      }
      #pragma unroll
      for (int nt = 0; nt < 4; ++nt){
        int row = wc * 64 + nt * 16 + l16;
        bf[nt] = *(const short8*)(Bt + row * 128 + (((ks * 4 + lg) ^ (row & 7)) << 4));
      }
      #pragma unroll
      for (int mt = 0; mt < 4; ++mt)
        #pragma unroll
        for (int nt = 0; nt < 4; ++nt)
          acc[mt][nt] = __builtin_amdgcn_mfma_f32_16x16x32_bf16(af[mt], bf[nt], acc[mt][nt], 0, 0, 0);
    }
    __syncthreads();
  }

  // Epilogue: C/D layout col = lane&15, row = (lane>>4)*4 + i
  #pragma unroll
  for (int mt = 0; mt < 4; ++mt){
    #pragma unroll
    for (int nt = 0; nt < 4; ++nt){
      #pragma unroll
      for (int i = 0; i < 4; ++i){
        int m = m0 + wr * 64 + mt * 16 + lg * 4 + i;
        int n = n0 + wc * 64 + nt * 16 + l16;
        float val = acc[mt][nt][i];
        if (EPI == 0){
          int part = n >> 10, c = n & 1023;
          int h = c >> 6,  d = c & 63;
          int b = m >> 11, t = m & 2047;
          unsigned short* dst = (part == 0) ? qd : ((part == 1) ? kd : vd);
          dst[(((size_t)(b * Hz + h)) * Tz + t) * DHz + d] = f2bf(val);
        } else {
          outf[(size_t)m * 1024 + n] = val;
        }
      }
    }
  }
}

// ---------------- RoPE in-place on q,k; fold (1/8)*log2(e) into q ------------
__global__ __launch_bounds__(256) void rope_kernel(unsigned short* __restrict__ qh,
                                                   unsigned short* __restrict__ kh,
                                                   const float* __restrict__ cosb,
                                                   const float* __restrict__ sinb){
  unsigned int idx = blockIdx.x * 256 + threadIdx.x;   // 2^23 total
  int i   = idx & 31;
  int row = (idx >> 5) & 131071;                        // B*H*T = 2^17 rows
  int buf = idx >> 22;
  unsigned short* p = (buf ? kh : qh) + (size_t)row * DHz + 2 * i;
  int t = row & (Tz - 1);
  float c = cosb[t * 32 + i], s = sinb[t * 32 + i];
  unsigned int pr = *(const unsigned int*)p;
  float x1 = bf2f((unsigned short)(pr & 0xffff));
  float x2 = bf2f((unsigned short)(pr >> 16));
  float r1 = x1 * c - x2 * s;
  float r2 = x1 * s + x2 * c;
  if (!buf){                                            // q: 1/sqrt(DH) * log2(e)
    const float qs = 0.125f * 1.4426950408889634f;
    r1 *= qs; r2 *= qs;
  }
  *(unsigned int*)p = (unsigned int)f2bf(r1) | ((unsigned int)f2bf(r2) << 16);
}

// ---------------- V transpose: [b,h,t,d] -> [b,h,d,t] (bf16) -----------------
__global__ __launch_bounds__(256)
void transpose_v(const unsigned short* __restrict__ src, unsigned short* __restrict__ dst){
  __shared__ __align__(16) unsigned short tl[64 * 72];
  const int tid = threadIdx.x;
  const int bh = blockIdx.x >> 5, tt = blockIdx.x & 31;
  const unsigned short* s = src + (((size_t)bh * Tz) + tt * 64) * DHz;
  {
    int r = tid >> 2, c0 = (tid & 3) * 16;
    short8 v0 = *(const short8*)(s + r * DHz + c0);
    short8 v1 = *(const short8*)(s + r * DHz + c0 + 8);
    *(short8*)(tl + r * 72 + c0) = v0;
    *(short8*)(tl + r * 72 + c0 + 8) = v1;
  }
  __syncthreads();
  const int d = tid & 63, w = tid >> 6;   // lane=d keeps LDS reads 2-way (free)
  short8 a, b;
  #pragma unroll
  for (int j = 0; j < 8; ++j) a[j] = (short)tl[(w * 16 + j) * 72 + d];
  #pragma unroll
  for (int j = 0; j < 8; ++j) b[j] = (short)tl[(w * 16 + 8 + j) * 72 + d];
  unsigned short* o = dst + ((size_t)bh * DHz + d) * Tz + tt * 64 + w * 16;
  *(short8*)(o)     = a;
  *(short8*)(o + 8) = b;
}

// ---------------- Flash attention (causal), swapped-QK^T, dbuf ---------------
// Block = 4 waves, 64 q-rows; wave owns 16 rows. KV tile = 64.
// S^T = mfma(K,Q): lane (lg,l16) holds q-row l16, kv = nt*16+lg*4+r.
__global__ __launch_bounds__(256)
void attn_fwd(const unsigned short* __restrict__ qh, const unsigned short* __restrict__ kh,
              const unsigned short* __restrict__ vt, unsigned short* __restrict__ y)
{
  __shared__ __align__(16) char lds[2*8192 + 2*8192 + 4*2304];   // K dbuf, VT dbuf, P
  const int tid  = threadIdx.x;
  const int lane = tid & 63, wid = tid >> 6;
  const int l16  = lane & 15, lg = lane >> 4;
  const int bh   = blockIdx.x;           // 0..63
  const int qt   = 31 - blockIdx.y;      // heavy blocks dispatched first

  const size_t base = (size_t)bh * Tz * DHz;
  const unsigned short* qb = qh + base;
  const unsigned short* kb = kh + base;
  const unsigned short* vb = vt + base;  // [d][T]

  const int qrow = qt * 64 + wid * 16 + l16;
  short8 qf[2];
  qf[0] = *(const short8*)(qb + (size_t)qrow * DHz + 0  + lg * 8);
  qf[1] = *(const short8*)(qb + (size_t)qrow * DHz + 32 + lg * 8);

  // staging geometry (per thread, loop-invariant)
  const int srow = tid >> 3;                       // 0..31 (+32 on it=1)
  const int scol = (tid & 7) ^ (srow & 7);         // source pre-swizzle
  const int kOff = srow * DHz + scol * 8;          // K rows stride 64
  const size_t vOff = (size_t)srow * Tz + scol * 8;// VT rows stride 2048
  char* const dst0 = (char*)lds + (wid * 64) * 16; // + it*4096, + buf sel

  auto STAGE = [&](int kt, int c){
    const unsigned short* Ks = kb + (size_t)kt * 64 * DHz;
    const unsigned short* Vs = vb + kt * 64;
    char* KD = (char*)lds + c * 8192;
    char* VD = (char*)lds + 16384 + c * 8192;
    #pragma unroll
    for (int it = 0; it < 2; ++it){
      gload_lds16(Ks + kOff + it * 32 * DHz, KD + (it * 256 + wid * 64) * 16);
      gload_lds16(Vs + vOff + (size_t)it * 32 * Tz, VD + (it * 256 + wid * 64) * 16);
    }
  };

  f32x4 o[4] = {};
  float m_r = -INFINITY, l_r = 0.f;
  unsigned short* Pw = (unsigned short*)(lds + 32768 + wid * 2304);

  int cur = 0;
  STAGE(0, 0);
  __syncthreads();

  for (int kt = 0; kt <= qt; ++kt){
    if (kt < qt) STAGE(kt + 1, cur ^ 1);

    char* KL = (char*)lds + cur * 8192;
    char* VL = (char*)lds + 16384 + cur * 8192;

    // S^T = K Q^T  (A=K rows kv, B=Q rows q)
    f32x4 s[4] = {};
    #pragma unroll
    for (int ks = 0; ks < 2; ++ks)
      #pragma unroll
      for (int nt = 0; nt < 4; ++nt){
        int row = nt * 16 + l16;
        short8 kf = *(const short8*)(KL + row * 128 + (((ks * 4 + lg) ^ (row & 7)) << 4));
        s[nt] = __builtin_amdgcn_mfma_f32_16x16x32_bf16(kf, qf[ks], s[nt], 0, 0, 0);
      }

    if (kt == qt){                        // causal mask on diagonal tile
      #pragma unroll
      for (int nt = 0; nt < 4; ++nt)
        #pragma unroll
        for (int r = 0; r < 4; ++r){
          int kv = kt * 64 + nt * 16 + lg * 4 + r;
          if (kv > qrow) s[nt][r] = -INFINITY;
        }
    }

    // online softmax in log2 domain; lane owns q-row l16 (16 values)
    float mx = fmaxf(fmaxf(fmaxf(s[0][0], s[0][1]), fmaxf(s[0][2], s[0][3])),
               fmaxf(fmaxf(fmaxf(s[1][0], s[1][1]), fmaxf(s[1][2], s[1][3])),
               fmaxf(fmaxf(fmaxf(s[2][0], s[2][1]), fmaxf(s[2][2], s[2][3])),
                     fmaxf(fmaxf(s[3][0], s[3][1]), fmaxf(s[3][2], s[3][3])))));
    mx = fmaxf(mx, __shfl_xor(mx, 16));
    mx = fmaxf(mx, __shfl_xor(mx, 32));

    if (!__all(mx - m_r <= 8.0f)){        // defer-max (T13): skip rescale mostly
      float mn = fmaxf(m_r, mx);
      float al = __builtin_amdgcn_exp2f(m_r - mn);
      #pragma unroll
      for (int i = 0; i < 4; ++i){
        float ali = __shfl(al, lg * 4 + i);      // broadcast to o-row layout
        o[0][i] *= ali; o[1][i] *= ali; o[2][i] *= ali; o[3][i] *= ali;
      }
      l_r *= al; m_r = mn;
    }

    float p[4][4]; float rs = 0.f;
    #pragma unroll
    for (int nt = 0; nt < 4; ++nt)
      #pragma unroll
      for (int r = 0; r < 4; ++r){
        float pv = __builtin_amdgcn_exp2f(s[nt][r] - m_r);
        p[nt][r] = pv; rs += pv;
      }
    rs += __shfl_xor(rs, 16);
    rs += __shfl_xor(rs, 32);
    l_r += rs;

    // P -> per-wave LDS: lane's 4 kv-consecutive values pack to one b64 store
    #pragma unroll
    for (int nt = 0; nt < 4; ++nt){
      unsigned long long w64 = (unsigned long long)packbf2(p[nt][0], p[nt][1])
                             | ((unsigned long long)packbf2(p[nt][2], p[nt][3]) << 32);
      *(unsigned long long*)(Pw + l16 * 72 + nt * 16 + lg * 4) = w64;
    }

    // O += P * V   (A=P rows q, B=VT rows d)
    #pragma unroll
    for (int ks = 0; ks < 2; ++ks){
      short8 pa = *(const short8*)((const char*)Pw + (l16 * 72 + ks * 32 + lg * 8) * 2);
      #pragma unroll
      for (int nt = 0; nt < 4; ++nt){
        int row = nt * 16 + l16;
        short8 vf = *(const short8*)(VL + row * 128 + (((ks * 4 + lg) ^ (row & 7)) << 4));
        o[nt] = __builtin_amdgcn_mfma_f32_16x16x32_bf16(pa, vf, o[nt], 0, 0, 0);
      }
    }

    __syncthreads();                       // next buffer staged + all reads done
    cur ^= 1;
  }

  // epilogue: normalize, write y [B,T,C] bf16; o rows q=lg*4+i, cols d=nt*16+l16
  const int b = bh >> 4, h = bh & 15;
  unsigned short* yb = y + ((size_t)b * Tz + qt * 64 + wid * 16) * Cz + h * 64;
  #pragma unroll
  for (int i = 0; i < 4; ++i){
    float inv = 1.f / __shfl(l_r, lg * 4 + i);
    int qr = lg * 4 + i;
    #pragma unroll
    for (int nt = 0; nt < 4; ++nt)
      yb[(size_t)qr * Cz + nt * 16 + l16] = f2bf(o[nt][i] * inv);
  }
}

// ---------------- launcher ----------------
extern "C" void kernel_launch(void* const* d_in, const int* in_sizes, int n_in,
                              void* d_out, int out_size, void* d_ws, size_t ws_size,
                              hipStream_t stream)
{
  const float* x    = (const float*)d_in[0];
  const float* cosb = (const float*)d_in[1];
  const float* sinb = (const float*)d_in[2];
  const float* Wqkv = (const float*)d_in[3];
  const float* Wo   = (const float*)d_in[4];
  float* out = (float*)d_out;

  char* ws = (char*)d_ws;
  // region 0 (16MB): xb (gemm1 input), then reused as V^T (xb dead after gemm1)
  unsigned short* xb    = (unsigned short*)(ws);
  unsigned short* vtb   = (unsigned short*)(ws);
  unsigned short* wqkvb = (unsigned short*)(ws + 16777216);      // 6 MB
  unsigned short* wob   = (unsigned short*)(ws + 23068672);      // 2 MB
  unsigned short* qhb   = (unsigned short*)(ws + 25165824);      // 16 MB
  unsigned short* khb   = (unsigned short*)(ws + 41943040);      // 16 MB
  unsigned short* vhb   = (unsigned short*)(ws + 58720256);      // 16 MB, dead after transpose
  unsigned short* ybuf  = vhb;                                   // y reuses vhb region
  // total 72 MB

  cvt_bf16<<<8192, 256, 0, stream>>>(x,    xb,    Mz * Cz);
  cvt_bf16<<<3072, 256, 0, stream>>>(Wqkv, wqkvb, 3 * Cz * Cz);
  cvt_bf16<<<1024, 256, 0, stream>>>(Wo,   wob,   Cz * Cz);

  dim3 g1(24, 64);   // N/128 = 24, M/128 = 64
  gemm_bt<0><<<g1, 256, 0, stream>>>(xb, wqkvb, Cz, qhb, khb, vhb, nullptr);

  rope_kernel<<<32768, 256, 0, stream>>>(qhb, khb, cosb, sinb);

  transpose_v<<<2048, 256, 0, stream>>>(vhb, vtb);

  dim3 g2(64, 32);   // (b*h), q-tile (remapped heavy-first inside)
  attn_fwd<<<g2, 256, 0, stream>>>(qhb, khb, vtb, ybuf);

  dim3 g3(8, 64);    // N/128 = 8, M/128 = 64
  gemm_bt<1><<<g3, 256, 0, stream>>>(ybuf, wob, Cz, nullptr, nullptr, nullptr, out);
}

// Round 3
// 266.162 us; speedup vs baseline: 1.3374x; 1.0774x over previous
//
#include <hip/hip_runtime.h>
#include <math.h>

// Problem constants
#define Bz 4
#define Tz 2048
#define Cz 1024
#define Hz 16
#define DHz 64
#define Mz (Bz*Tz)          // 8192

typedef __attribute__((ext_vector_type(8))) short short8;
typedef __attribute__((ext_vector_type(4))) float f32x4;
typedef __attribute__((ext_vector_type(4))) float flt4;
typedef unsigned long long u64;

__device__ inline unsigned short f2bf(float f){
  union { float f; unsigned int u; } x; x.f = f;
  unsigned int r = x.u + 0x7fffu + ((x.u >> 16) & 1u);
  return (unsigned short)(r >> 16);
}
__device__ inline float bf2f(unsigned short b){
  union { unsigned int u; float f; } x; x.u = ((unsigned int)b) << 16; return x.f;
}
// truncating pack of two f32 -> bf16x2 in ONE v_perm_b32
__device__ inline unsigned int packbf2(float lo, float hi){
  union { float f; unsigned int u; } a, b; a.f = lo; b.f = hi;
  return __builtin_amdgcn_perm(b.u, a.u, 0x07060302u);
}

__device__ inline void gload_lds16(const unsigned short* g, char* l){
  __builtin_amdgcn_global_load_lds((const __attribute__((address_space(1))) unsigned int*)g,
                                   (__attribute__((address_space(3))) unsigned int*)l,
                                   16, 0, 0);
}

// ---------------- fused fp32 -> bf16 convert (x, Wqkv, Wo) -------------------
#define NXE 8388608
#define NW1 3145728
#define NW2 1048576
__global__ __launch_bounds__(256) void cvt_all(const float* __restrict__ x,
                                               const float* __restrict__ wq,
                                               const float* __restrict__ wo,
                                               unsigned short* __restrict__ xb,
                                               unsigned short* __restrict__ wqb,
                                               unsigned short* __restrict__ wob){
  int i = (blockIdx.x * 256 + threadIdx.x) * 4;
  const float* s; unsigned short* d;
  if (i < NXE){ s = x + i; d = xb + i; }
  else if (i < NXE + NW1){ s = wq + (i - NXE); d = wqb + (i - NXE); }
  else { s = wo + (i - NXE - NW1); d = wob + (i - NXE - NW1); }
  flt4 v = *(const flt4*)s;
  u64 pack = (u64)f2bf(v.x) | ((u64)f2bf(v.y) << 16)
           | ((u64)f2bf(v.z) << 32) | ((u64)f2bf(v.w) << 48);
  *(u64*)d = pack;
}

// ---------------- GEMM: C = A * B^T (A: MxK, Bw: NxK, both bf16 row-major) ----
// EPI==0: q/k scatter to [B,H,T,DH]; v quadrant stores V^T [B,H,DH,T] packed.
// EPI==1: plain fp32 store.
template<int EPI>
__global__ __launch_bounds__(256)
void gemm_bt(const unsigned short* __restrict__ A, const unsigned short* __restrict__ Bw,
             const int K,
             unsigned short* __restrict__ qd, unsigned short* __restrict__ kd,
             unsigned short* __restrict__ vd, float* __restrict__ outf)
{
  __shared__ __align__(16) char lds[32768];
  char* At = lds;           // [128 rows][64 bf16 = 128B], swizzled content
  char* Bt = lds + 16384;

  const int tid  = threadIdx.x;
  const int lane = tid & 63, wid = tid >> 6;
  const int l16  = lane & 15, lg = lane >> 4;
  const int wr   = wid >> 1, wc = wid & 1;
  const int m0   = blockIdx.y * 128, n0 = blockIdx.x * 128;

  f32x4 acc[4][4] = {};
  const int nk = K >> 6;

  for (int kt = 0; kt < nk; ++kt){
    const unsigned short* As = A  + (size_t)m0 * K + kt * 64;
    const unsigned short* Bs = Bw + (size_t)n0 * K + kt * 64;
    #pragma unroll
    for (int it = 0; it < 4; ++it){
      int id  = it * 256 + tid;
      int row = id >> 3, c = id & 7;
      int sc  = c ^ (row & 7);                 // pre-swizzle global source
      char* dA = At + (it * 256 + wid * 64) * 16;
      char* dB = Bt + (it * 256 + wid * 64) * 16;
      gload_lds16(As + (size_t)row * K + sc * 8, dA);
      gload_lds16(Bs + (size_t)row * K + sc * 8, dB);
    }
    __syncthreads();

    #pragma unroll
    for (int ks = 0; ks < 2; ++ks){
      short8 af[4], bf[4];
      #pragma unroll
      for (int mt = 0; mt < 4; ++mt){
        int row = wr * 64 + mt * 16 + l16;
        af[mt] = *(const short8*)(At + row * 128 + (((ks * 4 + lg) ^ (row & 7)) << 4));
      }
      #pragma unroll
      for (int nt = 0; nt < 4; ++nt){
        int row = wc * 64 + nt * 16 + l16;
        bf[nt] = *(const short8*)(Bt + row * 128 + (((ks * 4 + lg) ^ (row & 7)) << 4));
      }
      #pragma unroll
      for (int mt = 0; mt < 4; ++mt)
        #pragma unroll
        for (int nt = 0; nt < 4; ++nt)
          acc[mt][nt] = __builtin_amdgcn_mfma_f32_16x16x32_bf16(af[mt], bf[nt], acc[mt][nt], 0, 0, 0);
    }
    __syncthreads();
  }

  // Epilogue. C/D layout: col = lane&15, row = (lane>>4)*4 + i
  if (EPI == 1){
    #pragma unroll
    for (int mt = 0; mt < 4; ++mt)
      #pragma unroll
      for (int nt = 0; nt < 4; ++nt)
        #pragma unroll
        for (int i = 0; i < 4; ++i){
          int m = m0 + wr * 64 + mt * 16 + lg * 4 + i;
          int n = n0 + wc * 64 + nt * 16 + l16;
          outf[(size_t)m * 1024 + n] = acc[mt][nt][i];
        }
  } else {
    const int part = n0 >> 10;                 // uniform per block (tiles don't cross)
    if (part < 2){
      unsigned short* dst = part ? kd : qd;
      #pragma unroll
      for (int mt = 0; mt < 4; ++mt)
        #pragma unroll
        for (int nt = 0; nt < 4; ++nt)
          #pragma unroll
          for (int i = 0; i < 4; ++i){
            int m = m0 + wr * 64 + mt * 16 + lg * 4 + i;
            int n = (n0 & 1023) + wc * 64 + nt * 16 + l16;
            int h = n >> 6, d = n & 63;
            int b = m >> 11, t = m & 2047;
            dst[(((size_t)(b * Hz + h)) * Tz + t) * DHz + d] = f2bf(acc[mt][nt][i]);
          }
    } else {
      // V^T store: rows (b,h,d), cols t; lane's 4 acc entries are t-contiguous
      #pragma unroll
      for (int mt = 0; mt < 4; ++mt)
        #pragma unroll
        for (int nt = 0; nt < 4; ++nt){
          int m = m0 + wr * 64 + mt * 16 + lg * 4;
          int n = (n0 & 1023) + wc * 64 + nt * 16 + l16;
          int h = n >> 6, d = n & 63;
          int b = m >> 11, t = m & 2047;
          u64 w = (u64)f2bf(acc[mt][nt][0]) | ((u64)f2bf(acc[mt][nt][1]) << 16)
                | ((u64)f2bf(acc[mt][nt][2]) << 32) | ((u64)f2bf(acc[mt][nt][3]) << 48);
          *(u64*)(vd + (((size_t)(b * Hz + h)) * DHz + d) * Tz + t) = w;
        }
    }
  }
}

// ---------------- RoPE in-place on q,k; fold (1/8)*log2(e) into q ------------
__global__ __launch_bounds__(256) void rope_kernel(unsigned short* __restrict__ qh,
                                                   unsigned short* __restrict__ kh,
                                                   const float* __restrict__ cosb,
                                                   const float* __restrict__ sinb){
  unsigned int idx = blockIdx.x * 256 + threadIdx.x;   // 2^21 total
  int quad = idx & 7;
  int row  = (idx >> 3) & 131071;                      // B*H*T rows
  int buf  = idx >> 20;
  unsigned short* p = (buf ? kh : qh) + (size_t)row * DHz + quad * 8;
  int t = row & (Tz - 1);
  flt4 c = *(const flt4*)(cosb + t * 32 + quad * 4);
  flt4 s = *(const flt4*)(sinb + t * 32 + quad * 4);
  short8 v = *(const short8*)p;
  const float qs = 0.125f * 1.4426950408889634f;       // 1/sqrt(DH) * log2(e) for q
  float sc = buf ? 1.0f : qs;
  short8 o;
  #pragma unroll
  for (int j = 0; j < 4; ++j){
    float x1 = bf2f((unsigned short)v[2*j]);
    float x2 = bf2f((unsigned short)v[2*j+1]);
    float r1 = (x1 * c[j] - x2 * s[j]) * sc;
    float r2 = (x1 * s[j] + x2 * c[j]) * sc;
    o[2*j]   = (short)f2bf(r1);
    o[2*j+1] = (short)f2bf(r2);
  }
  *(short8*)p = o;
}

// ---------------- Flash attention (causal), swapped-QK^T, O^T layout ---------
// Block = 4 waves, 64 q-rows; wave owns 16 rows. KV tile = 64.
// S^T = mfma(K,Q): lane's q = l16, kv = nt*16+lg*4+r  -> softmax per-lane.
// O^T = mfma(V^T,P): cols q = l16 -> rescale & epilogue need no shuffles.
__global__ __launch_bounds__(256)
void attn_fwd(const unsigned short* __restrict__ qh, const unsigned short* __restrict__ kh,
              const unsigned short* __restrict__ vt, unsigned short* __restrict__ y)
{
  __shared__ __align__(16) char lds[2*8192 + 2*8192 + 4*2304];   // K dbuf, VT dbuf, P
  const int tid  = threadIdx.x;
  const int lane = tid & 63, wid = tid >> 6;
  const int l16  = lane & 15, lg = lane >> 4;
  const int bh   = blockIdx.x;           // 0..63
  const int qt   = 31 - blockIdx.y;      // heavy blocks dispatched first

  const size_t base = (size_t)bh * Tz * DHz;
  const unsigned short* qb = qh + base;
  const unsigned short* kb = kh + base;
  const unsigned short* vb = vt + base;  // [d][T]

  const int qrow = qt * 64 + wid * 16 + l16;
  short8 qf[2];
  qf[0] = *(const short8*)(qb + (size_t)qrow * DHz + 0  + lg * 8);
  qf[1] = *(const short8*)(qb + (size_t)qrow * DHz + 32 + lg * 8);

  // loop-invariant LDS fragment offsets (rows nt*16+l16, swizzled): +nt*2048 imm
  const int x07 = l16 & 7;
  const int fo0 = l16 * 128 + (((0 + lg) ^ x07) << 4);
  const int fo1 = l16 * 128 + (((4 + lg) ^ x07) << 4);
  // P region (per wave), byte offsets
  char* const Pb  = (char*)lds + 32768 + wid * 2304;
  const int pwo = (l16 * 72 + lg * 4) * 2;    // + nt*32 imm
  const int pro = (l16 * 72 + lg * 8) * 2;    // + ks*64 imm

  // staging geometry (per thread, loop-invariant)
  const int srow = tid >> 3;                       // 0..31 (+32 on it=1)
  const int scol = (tid & 7) ^ (srow & 7);         // source pre-swizzle
  const int kOff = srow * DHz + scol * 8;          // K rows stride 64
  const size_t vOff = (size_t)srow * Tz + scol * 8;// VT rows stride 2048

  auto STAGE = [&](int kt, int c){
    const unsigned short* Ks = kb + (size_t)kt * 64 * DHz;
    const unsigned short* Vs = vb + kt * 64;
    char* KD = (char*)lds + c * 8192;
    char* VD = (char*)lds + 16384 + c * 8192;
    #pragma unroll
    for (int it = 0; it < 2; ++it){
      gload_lds16(Ks + kOff + it * 32 * DHz, KD + it * 4096 + wid * 1024);
      gload_lds16(Vs + vOff + (size_t)it * 32 * Tz, VD + it * 4096 + wid * 1024);
    }
  };

  short8 ones;
  #pragma unroll
  for (int j = 0; j < 8; ++j) ones[j] = (short)0x3F80;   // bf16 1.0

  f32x4 o[4] = {};
  f32x4 lsum = {};
  float m_r = -INFINITY;

  int cur = 0;
  STAGE(0, 0);
  __syncthreads();

  for (int kt = 0; kt <= qt; ++kt){
    if (kt < qt) STAGE(kt + 1, cur ^ 1);

    const char* KL = (const char*)lds + cur * 8192;
    const char* VL = (const char*)lds + 16384 + cur * 8192;

    // S^T = K Q^T
    f32x4 s[4] = {};
    __builtin_amdgcn_s_setprio(1);
    #pragma unroll
    for (int nt = 0; nt < 4; ++nt){
      short8 kf = *(const short8*)(KL + fo0 + nt * 2048);
      s[nt] = __builtin_amdgcn_mfma_f32_16x16x32_bf16(kf, qf[0], s[nt], 0, 0, 0);
    }
    #pragma unroll
    for (int nt = 0; nt < 4; ++nt){
      short8 kf = *(const short8*)(KL + fo1 + nt * 2048);
      s[nt] = __builtin_amdgcn_mfma_f32_16x16x32_bf16(kf, qf[1], s[nt], 0, 0, 0);
    }
    __builtin_amdgcn_s_setprio(0);

    if (kt == qt){                        // causal mask on diagonal tile
      #pragma unroll
      for (int nt = 0; nt < 4; ++nt)
        #pragma unroll
        for (int r = 0; r < 4; ++r){
          int kv = kt * 64 + nt * 16 + lg * 4 + r;
          if (kv > qrow) s[nt][r] = -INFINITY;
        }
    }

    // per-lane row max (q = l16), reduce across lg groups
    float mx = fmaxf(fmaxf(fmaxf(fmaxf(s[0][0], s[0][1]), fmaxf(s[0][2], s[0][3])),
                           fmaxf(fmaxf(s[1][0], s[1][1]), fmaxf(s[1][2], s[1][3]))),
                     fmaxf(fmaxf(fmaxf(s[2][0], s[2][1]), fmaxf(s[2][2], s[2][3])),
                           fmaxf(fmaxf(s[3][0], s[3][1]), fmaxf(s[3][2], s[3][3]))));
    mx = fmaxf(mx, __shfl_xor(mx, 16));
    mx = fmaxf(mx, __shfl_xor(mx, 32));

    if (!__all(mx - m_r <= 8.0f)){        // defer-max (T13)
      float mn = fmaxf(m_r, mx);
      float al = __builtin_amdgcn_exp2f(m_r - mn);
      #pragma unroll
      for (int nt = 0; nt < 4; ++nt)
        #pragma unroll
        for (int i = 0; i < 4; ++i) o[nt][i] *= al;
      #pragma unroll
      for (int i = 0; i < 4; ++i) lsum[i] *= al;
      m_r = mn;
    }

    // P = exp2(S - m), pack via v_perm, store to per-wave LDS
    #pragma unroll
    for (int nt = 0; nt < 4; ++nt){
      float p0 = __builtin_amdgcn_exp2f(s[nt][0] - m_r);
      float p1 = __builtin_amdgcn_exp2f(s[nt][1] - m_r);
      float p2 = __builtin_amdgcn_exp2f(s[nt][2] - m_r);
      float p3 = __builtin_amdgcn_exp2f(s[nt][3] - m_r);
      u64 w = (u64)packbf2(p0, p1) | ((u64)packbf2(p2, p3) << 32);
      *(u64*)(Pb + pwo + nt * 32) = w;
    }

    // O^T += V^T P ; row-sums via ones-MFMA
    __builtin_amdgcn_s_setprio(1);
    #pragma unroll
    for (int ks = 0; ks < 2; ++ks){
      short8 pa = *(const short8*)(Pb + pro + ks * 64);
      lsum = __builtin_amdgcn_mfma_f32_16x16x32_bf16(ones, pa, lsum, 0, 0, 0);
      const int fo = ks ? fo1 : fo0;
      #pragma unroll
      for (int nt = 0; nt < 4; ++nt){
        short8 vf = *(const short8*)(VL + fo + nt * 2048);
        o[nt] = __builtin_amdgcn_mfma_f32_16x16x32_bf16(vf, pa, o[nt], 0, 0, 0);
      }
    }
    __builtin_amdgcn_s_setprio(0);

    __syncthreads();                       // next buffer staged + all reads done
    cur ^= 1;
  }

  // epilogue: O^T rows d = nt*16+lg*4+i, cols q = l16 (all per-lane)
  const int b = bh >> 4, h = bh & 15;
  const int row = qt * 64 + wid * 16 + l16;
  unsigned short* yb = y + ((size_t)b * Tz + row) * Cz + h * 64 + lg * 4;
  float inv = 1.f / lsum[0];
  #pragma unroll
  for (int nt = 0; nt < 4; ++nt){
    u64 w = (u64)f2bf(o[nt][0] * inv) | ((u64)f2bf(o[nt][1] * inv) << 16)
          | ((u64)f2bf(o[nt][2] * inv) << 32) | ((u64)f2bf(o[nt][3] * inv) << 48);
    *(u64*)(yb + nt * 16) = w;
  }
}

// ---------------- launcher ----------------
extern "C" void kernel_launch(void* const* d_in, const int* in_sizes, int n_in,
                              void* d_out, int out_size, void* d_ws, size_t ws_size,
                              hipStream_t stream)
{
  const float* x    = (const float*)d_in[0];
  const float* cosb = (const float*)d_in[1];
  const float* sinb = (const float*)d_in[2];
  const float* Wqkv = (const float*)d_in[3];
  const float* Wo   = (const float*)d_in[4];
  float* out = (float*)d_out;

  char* ws = (char*)d_ws;
  unsigned short* xb    = (unsigned short*)(ws);                 // 16 MB, dead after gemm1
  unsigned short* ybuf  = xb;                                    // y reuses region 0
  unsigned short* wqkvb = (unsigned short*)(ws + 16777216);      // 6 MB
  unsigned short* wob   = (unsigned short*)(ws + 23068672);      // 2 MB
  unsigned short* qhb   = (unsigned short*)(ws + 25165824);      // 16 MB
  unsigned short* khb   = (unsigned short*)(ws + 41943040);      // 16 MB
  unsigned short* vtb   = (unsigned short*)(ws + 58720256);      // 16 MB (V^T direct)
  // total 72 MB

  cvt_all<<<12288, 256, 0, stream>>>(x, Wqkv, Wo, xb, wqkvb, wob);

  dim3 g1(24, 64);   // N/128 = 24, M/128 = 64
  gemm_bt<0><<<g1, 256, 0, stream>>>(xb, wqkvb, Cz, qhb, khb, vtb, nullptr);

  rope_kernel<<<8192, 256, 0, stream>>>(qhb, khb, cosb, sinb);

  dim3 g2(64, 32);   // (b*h), q-tile (remapped heavy-first inside)
  attn_fwd<<<g2, 256, 0, stream>>>(qhb, khb, vtb, ybuf);

  dim3 g3(8, 64);    // N/128 = 8, M/128 = 64
  gemm_bt<1><<<g3, 256, 0, stream>>>(ybuf, wob, Cz, nullptr, nullptr, nullptr, out);
}